// Round 4
// baseline (1174.451 us; speedup 1.0000x reference)
//
#include <hip/hip_runtime.h>
#include <math.h>

#define B_ 256
#define L_ 2048
#define T_ 64
#define TS_ 66   // TRANS_SIZE
#define START_ 64
#define END_ 65

// Kernel A: gold-path ("real") score per batch, accumulated NEGATIVELY into out.
// out -= (emission + trans_pairs + first + last) / B
__global__ __launch_bounds__(256) void crf_real_kernel(
    const float* __restrict__ features, const int* __restrict__ tags,
    const int* __restrict__ lengths, const float* __restrict__ trans,
    float* __restrict__ out)
{
    const int b = blockIdx.x;
    const int tid = threadIdx.x;
    __shared__ float tl[TS_ * TS_];
    for (int i = tid; i < TS_ * TS_; i += 256) tl[i] = trans[i];
    __syncthreads();

    const int len = lengths[b];
    const int* tg = tags + (size_t)b * L_;
    const float* fb = features + (size_t)b * L_ * T_;

    float local = 0.f;
    for (int t = tid; t < len; t += 256) {
        local += fb[(size_t)t * T_ + tg[t]];
    }
    for (int t = tid; t + 1 < len; t += 256) {
        local += tl[tg[t] * TS_ + tg[t + 1]];
    }
    #pragma unroll
    for (int d = 32; d >= 1; d >>= 1) local += __shfl_xor(local, d, 64);
    __shared__ float wsum[4];
    if ((tid & 63) == 0) wsum[tid >> 6] = local;
    __syncthreads();
    if (tid == 0) {
        float tot = wsum[0] + wsum[1] + wsum[2] + wsum[3];
        tot += tl[START_ * TS_ + tg[0]];
        tot += tl[tg[len - 1] * TS_ + END_];
        atomicAdd(out, -tot * (1.0f / (float)B_));
    }
}

// Kernel B: forward algorithm in PROBABILITY space with exact power-of-2
// rescaling. One wave per batch, lane j = tag. Per step the critical path is
// only: ds_write P -> 16x broadcast ds_read_b128 -> 64 FMA -> 1 mul.
// exp(feat) is computed in the prefetch shadow; rescale uses lag-1
// readfirstlane exponent extraction (K accumulates exactly as an int).
__global__ __launch_bounds__(64) void crf_fwd_kernel(
    const float* __restrict__ features, const int* __restrict__ lengths,
    const float* __restrict__ trans, float* __restrict__ out)
{
    const int b = blockIdx.x;
    const int j = threadIdx.x;   // tag index 0..63
    const int len = lengths[b];
    const float* fb = features + (size_t)b * L_ * T_;

    // E column j in registers: Ecol[i] = exp(trans[i][j])  (coalesced loads)
    float Ecol[T_];
    #pragma unroll
    for (int i = 0; i < T_; ++i) Ecol[i] = __expf(trans[i * TS_ + j]);
    const float EEnd = __expf(trans[j * TS_ + END_]);

    // P_j = exp(alpha0_j), alpha0 = trans[START][j] + feat[0][j]  (range ~e^±6)
    float P = __expf(trans[START_ * TS_ + j] + fb[j]);
    int   K = 0;      // exact accumulated power-of-two shifts
    float s = 1.0f;   // scale to fold into the next step's multiply

    __shared__ __align__(16) float pbuf[T_];

    // exp(feature) prefetch pipeline, depth 3 (indices clamped in-bounds)
    float fe0 = __expf(fb[(size_t)1 * T_ + j]);
    float fe1 = __expf(fb[(size_t)2 * T_ + j]);
    float fe2 = __expf(fb[(size_t)3 * T_ + j]);

    #pragma unroll 4
    for (int t = 1; t < len; ++t) {
        // Single wave: DS ops complete in order per wave, so write->read RAW
        // through LDS needs no barrier; compiler orders via alias analysis
        // and inserts lgkmcnt before VALU use.
        pbuf[j] = P;

        float f = fe0 * s;          // off critical path (fe0, s ready early)
        fe0 = fe1; fe1 = fe2;
        int tp = t + 3; if (tp > L_ - 1) tp = L_ - 1;
        fe2 = __expf(fb[(size_t)tp * T_ + j]);

        const float4* p4 = (const float4*)pbuf;
        float a0 = 0.f, a1 = 0.f, a2 = 0.f, a3 = 0.f;
        #pragma unroll
        for (int k = 0; k < 16; ++k) {
            float4 pv = p4[k];      // same address all lanes -> LDS broadcast
            a0 = fmaf(pv.x, Ecol[4 * k + 0], a0);
            a1 = fmaf(pv.y, Ecol[4 * k + 1], a1);
            a2 = fmaf(pv.z, Ecol[4 * k + 2], a2);
            a3 = fmaf(pv.w, Ecol[4 * k + 3], a3);
        }
        float dot = (a0 + a1) + (a2 + a3);
        P = dot * f;

        s = 1.0f;
        if ((t & 3) == 0) {
            // normalize so lane 0's P returns to [1,2) next step (lag-1)
            int ru = __builtin_amdgcn_readfirstlane(__float_as_int(P));
            int k  = ((ru >> 23) & 255) - 127;
            K += k;
            s = __int_as_float((127 - k) << 23);   // 2^-k
        }
    }

    // logZ = log(sum_j P_j * exp(trans[j][END])) + K*ln2
    float v = P * EEnd;
    #pragma unroll
    for (int d = 32; d >= 1; d >>= 1) v += __shfl_xor(v, d, 64);
    if (j == 0) {
        float logZ = __logf(v) + (float)K * 0.69314718055994531f;
        atomicAdd(out, logZ * (1.0f / (float)B_));
    }
}

extern "C" void kernel_launch(void* const* d_in, const int* in_sizes, int n_in,
                              void* d_out, int out_size, void* d_ws, size_t ws_size,
                              hipStream_t stream) {
    const float* features    = (const float*)d_in[0];
    const int*   tags        = (const int*)d_in[1];
    const int*   lengths     = (const int*)d_in[2];
    const float* transitions = (const float*)d_in[3];
    float* out = (float*)d_out;

    hipMemsetAsync(out, 0, sizeof(float), stream);

    // fwd first (1 wave/CU, latency-bound); real kernel's waves co-schedule
    // on the idle SIMDs and are fully hidden. Both atomicAdd into out.
    crf_fwd_kernel<<<B_, 64, 0, stream>>>(features, lengths, transitions, out);
    crf_real_kernel<<<B_, 256, 0, stream>>>(features, tags, lengths, transitions, out);
}

// Round 5
// 706.684 us; speedup vs baseline: 1.6619x; 1.6619x over previous
//
#include <hip/hip_runtime.h>

#define B_ 256
#define L_ 2048
#define T_ 64
#define TS_ 66   // TRANS_SIZE
#define START_ 64
#define END_ 65

// Fused CRF loss kernel. grid = B, block = 128 (2 waves):
//   wave 0: forward algorithm (serial chain) in probability space
//   wave 1: gold-path score (gather-reduce), fully hidden under wave 0
// Both atomicAdd into out; no intra-block synchronization needed.
__global__ __launch_bounds__(128) void crf_fused_kernel(
    const float* __restrict__ features, const int* __restrict__ tags,
    const int* __restrict__ lengths, const float* __restrict__ trans,
    float* __restrict__ out)
{
    const int b    = blockIdx.x;
    const int lane = threadIdx.x & 63;
    const int wid  = threadIdx.x >> 6;
    const int len  = lengths[b];
    const float* fb = features + (size_t)b * (L_ * T_);

    if (wid == 1) {
        // ---- gold-path ("real") score, negated ----
        const int* tg = tags + (size_t)b * L_;
        float local = 0.f;
        for (int t = lane; t < len; t += 64)
            local += fb[(size_t)t * T_ + tg[t]];
        for (int t = lane; t + 1 < len; t += 64)
            local += trans[tg[t] * TS_ + tg[t + 1]];
        #pragma unroll
        for (int d = 32; d >= 1; d >>= 1) local += __shfl_xor(local, d, 64);
        if (lane == 0) {
            local += trans[START_ * TS_ + tg[0]];
            local += trans[tg[len - 1] * TS_ + END_];
            atomicAdd(out, -local * (1.0f / (float)B_));
        }
        return;
    }

    // ---- forward chain, probability space with exact pow2 rescaling ----
    const int j = lane;   // tag index
    float Ecol[T_];       // E column j in registers: exp(trans[i][j])
    #pragma unroll
    for (int i = 0; i < T_; ++i) Ecol[i] = __expf(trans[i * TS_ + j]);
    const float EEnd = __expf(trans[j * TS_ + END_]);

    float P = __expf(trans[START_ * TS_ + j] + fb[j]);
    int   K = 0;          // exact accumulated power-of-2 shifts

    __shared__ __align__(16) float pbuf[T_];

    const int lenc = len - 1;   // last valid feature row (>= 0)

    // Depth-8 prefetch ring of RAW feature values. exp() is applied one
    // step before consumption, so load->use distance is ~7 iterations
    // (the R4 version applied expf at fill time => load->use distance 0,
    // stalling one memory latency per step: the measured 1206 cy/step).
    // ring slot (r & 7) holds feature row r.
    float ring[8];
    #pragma unroll
    for (int r = 1; r <= 8; ++r) {
        const int rr = (r <= lenc) ? r : lenc;
        ring[r & 7] = fb[(size_t)rr * T_ + j];
    }
    float fcur = __expf(ring[1]);   // exp(feat[row 1])

    // pad to multiple of 8 so every ring index is compile-time static;
    // steps t >= len are masked (P unchanged) — rescale stays exact.
    const int pad = ((lenc + 7) >> 3) << 3;
    for (int tb = 1; tb <= pad; tb += 8) {
        #pragma unroll
        for (int u = 0; u < 8; ++u) {
            const int t = tb + u;          // tb ≡ 1 (mod 8) → (t+c)&7 static
            pbuf[j] = P;                   // single-wave RAW via in-order DS

            // rescale factor from PREVIOUS P — chain hides under LDS round
            const bool doresc = (((1 + u) & 3) == 0);
            int kk = 0; float srs = 1.0f;
            if (doresc) {
                int ru = __builtin_amdgcn_readfirstlane(__float_as_int(P));
                kk  = ((ru >> 23) & 255) - 127;
                srs = __int_as_float((127 - kk) << 23);   // 2^-kk
            }

            const float f = fcur;                          // exp(feat[t])
            fcur = __expf(ring[(u + 2) & 7]);              // row t+1, loaded 7 iters ago
            int tl8 = t + 8; if (tl8 > lenc) tl8 = lenc;
            ring[(u + 1) & 7] = fb[(size_t)tl8 * T_ + j];  // issue row t+8

            const float4* p4 = (const float4*)pbuf;
            float a0 = 0.f, a1 = 0.f, a2 = 0.f, a3 = 0.f;
            #pragma unroll
            for (int k = 0; k < 16; ++k) {
                float4 pv = p4[k];   // same address all lanes -> LDS broadcast
                a0 = fmaf(pv.x, Ecol[4 * k + 0], a0);
                a1 = fmaf(pv.y, Ecol[4 * k + 1], a1);
                a2 = fmaf(pv.z, Ecol[4 * k + 2], a2);
                a3 = fmaf(pv.w, Ecol[4 * k + 3], a3);
            }
            const float dot = (a0 + a1) + (a2 + a3);
            const float Pn  = dot * f;
            P = (t < len) ? Pn : P;                        // mask pad steps
            if (doresc) { K += kk; P *= srs; }             // exact, unconditional
        }
    }

    // logZ = log(sum_j P_j * exp(trans[j][END])) + K*ln2
    float v = P * EEnd;
    #pragma unroll
    for (int d = 32; d >= 1; d >>= 1) v += __shfl_xor(v, d, 64);
    if (j == 0) {
        float logZ = __logf(v) + (float)K * 0.69314718055994531f;
        atomicAdd(out, logZ * (1.0f / (float)B_));
    }
}

extern "C" void kernel_launch(void* const* d_in, const int* in_sizes, int n_in,
                              void* d_out, int out_size, void* d_ws, size_t ws_size,
                              hipStream_t stream) {
    const float* features    = (const float*)d_in[0];
    const int*   tags        = (const int*)d_in[1];
    const int*   lengths     = (const int*)d_in[2];
    const float* transitions = (const float*)d_in[3];
    float* out = (float*)d_out;

    hipMemsetAsync(out, 0, sizeof(float), stream);
    crf_fused_kernel<<<B_, 128, 0, stream>>>(features, tags, lengths, transitions, out);
}